// Round 7
// baseline (1059.969 us; speedup 1.0000x reference)
//
#include <hip/hip_runtime.h>
#include <hip/hip_bf16.h>

// DualPathModule: 2 layers x (t-path, b-path) Mamba2, bf16-MFMA version.
// HID=256, DIN=512, NHEADS=8, HEADP=64, DSTATE=64, CONVDIM=640, PROJ=1160 (padded 1280)
// t-path: 124 seqs x L=192 (strided in x); b-path: 384 seqs x L=62. M=23808.
// inproj output: zxh bf16 [M x 1152] (z 0..511 | conv-in 512..1151) + dtraw f32 [M x 8].

#define MTOK   23808
#define PROJP  1280   // padded WinT rows (cols 1160..1279 zero)
#define ZXW    1152   // zxh row stride (bf16)

typedef __attribute__((ext_vector_type(8))) short short8v;
typedef __attribute__((ext_vector_type(4))) short short4v;
typedef __attribute__((ext_vector_type(4))) float f32x4;

__device__ __forceinline__ float wave_sum64(float v) {
#pragma unroll
  for (int off = 32; off; off >>= 1) v += __shfl_xor(v, off, 64);
  return v;
}

__device__ __forceinline__ short f2bf(float f) {
  union { float f; unsigned u; } v; v.f = f;
  unsigned r = (v.u + 0x7fffu + ((v.u >> 16) & 1u)) >> 16;  // RNE
  return (short)r;
}
__device__ __forceinline__ float bf2f(short s) {
  union { unsigned u; float f; } v; v.u = ((unsigned)(unsigned short)s) << 16; return v.f;
}

// token m of t-path (seq = b*62+nb, time tt) -> flat offset in x (B,T,NB,H)
__device__ __forceinline__ long t_base(int m) {
  int seq = m / 192, tt = m - seq * 192;
  int b = seq / 62, nb = seq - b * 62;
  return ((long)((b * 192 + tt) * 62 + nb)) * 256;
}

// ---------------- weight transpose+cvt: dst[z][n][k] = src_z[k][n], n>=N zero-padded
__global__ __launch_bounds__(256) void k_wt(const float* __restrict__ tW,
                                            const float* __restrict__ bW,
                                            short* __restrict__ dst, int K, int N, int NP) {
  int z = blockIdx.z;
  const float* src = (z >> 1 ? bW : tW) + (long)(z & 1) * K * N;
  short* d = dst + (long)z * NP * K;
  int idx = blockIdx.x * 256 + threadIdx.x;
  if (idx >= NP * K) return;
  int n = idx / K, k = idx - n * K;
  d[idx] = (n < N) ? f2bf(src[(long)k * N + n]) : (short)0;
}

// ---------------- gather + rmsnorm over H=256 -> bufn[M x 256] bf16
template <bool TPATH>
__global__ __launch_bounds__(256) void k_rmsnorm_in(const float* __restrict__ xio,
                                                    const float* __restrict__ w,
                                                    short* __restrict__ outb) {
  int m = blockIdx.x * 4 + (threadIdx.x >> 6);
  int lane = threadIdx.x & 63;
  long base = TPATH ? t_base(m) : (long)m * 256;
  float4 v = *(const float4*)(xio + base + lane * 4);
  float ss = v.x * v.x + v.y * v.y + v.z * v.z + v.w * v.w;
  ss = wave_sum64(ss);
  float sc = rsqrtf(ss * (1.f / 256.f) + 1e-6f);
  float4 wv = *(const float4*)(w + lane * 4);
  short4v o;
  o[0] = f2bf(v.x * sc * wv.x); o[1] = f2bf(v.y * sc * wv.y);
  o[2] = f2bf(v.z * sc * wv.z); o[3] = f2bf(v.w * sc * wv.w);
  *(short4v*)(outb + (long)m * 256 + lane * 4) = o;
}

// ---------------- inproj MFMA GEMM: [M x 1280] = A[M x 256] . WT^T, bf16 out.
// Block 128x128, grid 10 x 186, XCD-chunk swizzled. n-tiles 0..8 -> zxh bf16;
// n-tile 9 -> dt cols 1152..1159 f32 to dtraw.
__global__ __launch_bounds__(256) void gemm_in(const short* __restrict__ A,
                                               const short* __restrict__ WT,
                                               short* __restrict__ zxh,
                                               float* __restrict__ dtraw) {
  // bijective chunk swizzle over 1860 blocks (q=232, r=4)
  int bid = blockIdx.y * 10 + blockIdx.x;
  int xcd = bid & 7, idx = bid >> 3;
  const int q = 232, r = 4;
  int wg = (xcd < r ? xcd * (q + 1) : r * (q + 1) + (xcd - r) * q) + idx;
  int bx = wg % 10, by = wg / 10;

  int w = threadIdx.x >> 6, lane = threadIdx.x & 63;
  int m0 = by * 128 + (w >> 1) * 64;
  int n0 = bx * 128 + (w & 1) * 64;
  int lr = lane & 15, lg = lane >> 4;
  f32x4 acc[4][4];
#pragma unroll
  for (int i = 0; i < 4; ++i)
#pragma unroll
    for (int j = 0; j < 4; ++j) acc[i][j] = (f32x4){0.f, 0.f, 0.f, 0.f};
  const short* Ap = A + (long)(m0 + lr) * 256 + lg * 8;
  const short* Bp = WT + (long)(n0 + lr) * 256 + lg * 8;
#pragma unroll 2
  for (int k0 = 0; k0 < 256; k0 += 32) {
    short8v a[4], b[4];
#pragma unroll
    for (int f = 0; f < 4; ++f) {
      a[f] = *(const short8v*)(Ap + (long)f * 16 * 256 + k0);
      b[f] = *(const short8v*)(Bp + (long)f * 16 * 256 + k0);
    }
#pragma unroll
    for (int i = 0; i < 4; ++i)
#pragma unroll
      for (int j = 0; j < 4; ++j)
        acc[i][j] = __builtin_amdgcn_mfma_f32_16x16x32_bf16(a[i], b[j], acc[i][j], 0, 0, 0);
  }
  if (n0 < ZXW) {
#pragma unroll
    for (int i = 0; i < 4; ++i)
#pragma unroll
      for (int j = 0; j < 4; ++j)
#pragma unroll
        for (int rr = 0; rr < 4; ++rr) {
          int m = m0 + i * 16 + lg * 4 + rr;
          zxh[(long)m * ZXW + n0 + j * 16 + lr] = f2bf(acc[i][j][rr]);
        }
  } else if (n0 == ZXW && lr < 8) {
#pragma unroll
    for (int i = 0; i < 4; ++i)
#pragma unroll
      for (int rr = 0; rr < 4; ++rr) {
        int m = m0 + i * 16 + lg * 4 + rr;
        dtraw[(long)m * 8 + lr] = acc[i][0][rr];
      }
  }
}

// ---------------- outproj MFMA GEMM + residual. EPI 1 = t-path scatter, 2 = b-path.
template <int EPI>
__global__ __launch_bounds__(256) void gemm_mfma(const short* __restrict__ A,
                                                 const short* __restrict__ WT,
                                                 float* __restrict__ C,
                                                 int K, int ldc) {
  int w = threadIdx.x >> 6, lane = threadIdx.x & 63;
  int m0 = blockIdx.y * 128 + (w >> 1) * 64;
  int n0 = blockIdx.x * 128 + (w & 1) * 64;
  int lr = lane & 15, lg = lane >> 4;
  f32x4 acc[4][4];
#pragma unroll
  for (int i = 0; i < 4; ++i)
#pragma unroll
    for (int j = 0; j < 4; ++j) acc[i][j] = (f32x4){0.f, 0.f, 0.f, 0.f};
  const short* Ap = A + (long)(m0 + lr) * K + lg * 8;
  const short* Bp = WT + (long)(n0 + lr) * K + lg * 8;
#pragma unroll 2
  for (int k0 = 0; k0 < K; k0 += 32) {
    short8v a[4], b[4];
#pragma unroll
    for (int f = 0; f < 4; ++f) {
      a[f] = *(const short8v*)(Ap + (long)f * 16 * K + k0);
      b[f] = *(const short8v*)(Bp + (long)f * 16 * K + k0);
    }
#pragma unroll
    for (int i = 0; i < 4; ++i)
#pragma unroll
      for (int j = 0; j < 4; ++j)
        acc[i][j] = __builtin_amdgcn_mfma_f32_16x16x32_bf16(a[i], b[j], acc[i][j], 0, 0, 0);
  }
#pragma unroll
  for (int i = 0; i < 4; ++i)
#pragma unroll
    for (int j = 0; j < 4; ++j)
#pragma unroll
      for (int rr = 0; rr < 4; ++rr) {
        int m = m0 + i * 16 + lg * 4 + rr;
        int n = n0 + j * 16 + lr;
        long base = (EPI == 1) ? t_base(m) : (long)m * 256;
        C[base + n] += acc[i][j][rr];
      }
}

// ---------------- causal depthwise conv(K=4) + silu, bf16 in -> xBC[M x 640] bf16
// 1 thread = 8 consecutive channels (short8v loads/store)
__global__ __launch_bounds__(256) void k_conv(const short* __restrict__ zin,
                                              const float* __restrict__ Wc,
                                              const float* __restrict__ bc,
                                              short* __restrict__ xBC, int L) {
  int idx = blockIdx.x * 256 + threadIdx.x;
  if (idx >= MTOK * 80) return;
  int m = idx / 80, c8 = (idx - m * 80) << 3;
  int tpos = m % L;
  float wv[8][4];
#pragma unroll
  for (int e = 0; e < 8; ++e) {
    float4 we = *(const float4*)(Wc + (c8 + e) * 4);
    wv[e][0] = we.x; wv[e][1] = we.y; wv[e][2] = we.z; wv[e][3] = we.w;
  }
  float acc[8];
  float4 b0 = *(const float4*)(bc + c8);
  float4 b1 = *(const float4*)(bc + c8 + 4);
  acc[0] = b0.x; acc[1] = b0.y; acc[2] = b0.z; acc[3] = b0.w;
  acc[4] = b1.x; acc[5] = b1.y; acc[6] = b1.z; acc[7] = b1.w;
  const short* base = zin + (long)m * ZXW + 512 + c8;
#pragma unroll
  for (int k = 0; k < 4; ++k) {
    int tt = tpos - 3 + k;
    if (tt >= 0) {
      short8v v = *(const short8v*)(base + (long)(k - 3) * ZXW);
#pragma unroll
      for (int e = 0; e < 8; ++e) acc[e] += wv[e][k] * bf2f(v[e]);
    }
  }
  short8v o;
#pragma unroll
  for (int e = 0; e < 8; ++e) o[e] = f2bf(acc[e] / (1.f + __expf(-acc[e])));
  *(short8v*)(xBC + (long)m * 640 + c8) = o;
}

// ---------------- fused softplus(dt) + per-(seq,head) inclusive scan of dt*A
__global__ __launch_bounds__(256) void k_scan(const float* __restrict__ dtraw,
                                              const float* __restrict__ dtbias,
                                              const float* __restrict__ A_log,
                                              float* __restrict__ dtb,
                                              float* __restrict__ cumb,
                                              int nseq, int L) {
  int wid = blockIdx.x * 4 + (threadIdx.x >> 6);
  if (wid >= nseq * 8) return;
  int seq = wid >> 3, h = wid & 7, lane = threadIdx.x & 63;
  float Ah = -__expf(A_log[h]);
  float bias = dtbias[h];
  float run = 0.f;
  for (int t0 = 0; t0 < L; t0 += 64) {
    int tt = t0 + lane;
    float d = 0.f;
    if (tt < L) {
      float v = dtraw[((long)seq * L + tt) * 8 + h] + bias;
      d = (v > 20.f) ? v : log1pf(__expf(v));
    }
    float s = d * Ah;
#pragma unroll
    for (int off = 1; off < 64; off <<= 1) {
      float o = __shfl_up(s, off, 64);
      if (lane >= off) s += o;
    }
    if (tt < L) {
      long m = (long)seq * L + tt;
      dtb[m * 8 + h] = d;
      cumb[m * 8 + h] = run + s;
    }
    run += __shfl(s, 63, 64);
  }
}

// ---------------- x transpose: xT[(seq*8+h)*64 + p][LP] = x[s][h*64+p], zero-padded s>=L
template <int L>
__global__ __launch_bounds__(256) void k_xt(const short* __restrict__ xbc,
                                            short* __restrict__ xT) {
  constexpr int LP = (L + 63) & ~63;
  int seq = blockIdx.x, h = blockIdx.y, st = blockIdx.z;
  __shared__ short tile[64][72];
  int t = threadIdx.x;
  for (int e = t; e < 512; e += 256) {
    int s = e >> 3, p8 = (e & 7) * 8;
    int sg = st * 64 + s;
    union { short8v v; short a[8]; } u;
    if (sg < L) u.v = *(const short8v*)(xbc + ((long)seq * L + sg) * 640 + h * 64 + p8);
    else {
#pragma unroll
      for (int j = 0; j < 8; ++j) u.a[j] = 0;
    }
    *(short8v*)&tile[s][p8] = u.v;
  }
  __syncthreads();
  for (int e = t; e < 512; e += 256) {
    int p = e >> 3, s8 = (e & 7) * 8;
    union { short8v v; short a[8]; } u;
#pragma unroll
    for (int j = 0; j < 8; ++j) u.a[j] = tile[s8 + j][p];
    *(short8v*)(xT + ((long)(seq * 8 + h) * 64 + p) * LP + st * 64 + s8) = u.v;
  }
}

// ---------------- SSD v4: shared-CB, in-register P. (unchanged from R5)
template <int L, int NCH>
__global__ __launch_bounds__(256) void k_ssd4(const short* __restrict__ xbc,
                                              const short* __restrict__ xT,
                                              const float* __restrict__ dtb,
                                              const float* __restrict__ cumb,
                                              const float* __restrict__ A_log,
                                              short* __restrict__ y) {
  constexpr int LP = (L + 63) & ~63;
  constexpr bool FULL = (L % 64) == 0;
  int hg = blockIdx.x, lt = blockIdx.y, seq = blockIdx.z;
  int tid = threadIdx.x, w = tid >> 6, lane = tid & 63;
  int lr = lane & 15, lg = lane >> 4;
  int h = hg * 4 + w;
  int l0 = lt * 64;

  __shared__ float s_cb[64 * 64];     // [l][s ^ ((l&7)<<2)] f32, 16KB
  __shared__ float s_cums[64][8];
  __shared__ float s_dts[64][8];

  float Ah = -__expf(A_log[h]);

  float cl[4], cpl[4];
#pragma unroll
  for (int i = 0; i < 4; ++i) {
    int lgl = l0 + i * 16 + lr;
    int lc = FULL ? lgl : (lgl < L ? lgl : L - 1);
    long m = (long)seq * L + lc;
    float cv = cumb[m * 8 + h];
    cl[i] = cv; cpl[i] = cv - dtb[m * 8 + h] * Ah;
  }

  f32x4 yacc[4][4];
#pragma unroll
  for (int i = 0; i < 4; ++i)
#pragma unroll
    for (int j = 0; j < 4; ++j) yacc[i][j] = (f32x4){0.f, 0.f, 0.f, 0.f};

  int crow = l0 + w * 16 + lr;
  if (!FULL) crow = crow < L ? crow : L - 1;
  const short* Cp = xbc + ((long)seq * L + crow) * 640 + 576 + lg * 8;

  for (int c = 0; c < NCH; ++c) {
    int c64 = c * 64;

    if (tid < 128) {
      int rr = tid & 63;
      int sg = c64 + rr;
      int sc = FULL ? sg : (sg < L ? sg : L - 1);
      const float* src = (tid < 64 ? cumb : dtb) + ((long)seq * L + sc) * 8;
      float4 v0 = *(const float4*)(src);
      float4 v1 = *(const float4*)(src + 4);
      float* dstp = (tid < 64 ? &s_cums[rr][0] : &s_dts[rr][0]);
      *(float4*)dstp = v0;
      *(float4*)(dstp + 4) = v1;
    }

    f32x4 cb4[4];
#pragma unroll
    for (int j = 0; j < 4; ++j) cb4[j] = (f32x4){0.f, 0.f, 0.f, 0.f};
#pragma unroll
    for (int ks = 0; ks < 2; ++ks) {
      short8v a = *(const short8v*)(Cp + ks * 32);
#pragma unroll
      for (int j = 0; j < 4; ++j) {
        int srow = c64 + j * 16 + lr;
        if (!FULL) srow = srow < L ? srow : L - 1;
        short8v b = *(const short8v*)(xbc + ((long)seq * L + srow) * 640 + 512 + lg * 8 + ks * 32);
        cb4[j] = __builtin_amdgcn_mfma_f32_16x16x32_bf16(a, b, cb4[j], 0, 0, 0);
      }
    }
#pragma unroll
    for (int j = 0; j < 4; ++j)
#pragma unroll
      for (int rr = 0; rr < 4; ++rr) {
        int lloc = w * 16 + lg * 4 + rr;
        int sloc = j * 16 + lr;
        s_cb[lloc * 64 + (sloc ^ ((lloc & 7) << 2))] = cb4[j][rr];
      }

    short8v bx[2][4];
#pragma unroll
    for (int ks = 0; ks < 2; ++ks)
#pragma unroll
      for (int j = 0; j < 4; ++j)
        bx[ks][j] = *(const short8v*)(xT + ((long)(seq * 8 + h) * 64 + j * 16 + lr) * LP +
                                      c64 + ks * 32 + lg * 8);

    __syncthreads();

#pragma unroll
    for (int ks = 0; ks < 2; ++ks) {
      int sbase = ks * 32 + lg * 8;
      float cs[8], cps[8], dss[8];
#pragma unroll
      for (int e = 0; e < 8; ++e) {
        int sl = sbase + e;
        float cv = s_cums[sl][h];
        float dv = s_dts[sl][h];
        cs[e] = cv; cps[e] = cv - dv * Ah; dss[e] = dv;
      }
#pragma unroll
      for (int i = 0; i < 4; ++i) {
        int R = i * 16 + lr;
        int lgl = l0 + R;
        int sw = (R & 7) << 2;
        int c0 = sbase ^ sw;
        const float* cbrow = &s_cb[R * 64];
        f32x4 lo = *(const f32x4*)(cbrow + c0);
        f32x4 hi = *(const f32x4*)(cbrow + (c0 ^ 4));
        short8v a;
#pragma unroll
        for (int e = 0; e < 8; ++e) {
          int sgl = c64 + sbase + e;
          float cbv = (e < 4) ? lo[e & 3] : hi[e & 3];
          float wgt = 0.f;
          if (sgl <= lgl) wgt += __expf(cl[i] - cs[e]);
          if (sgl >= lgl) wgt += __expf(cps[e] - cpl[i]);
          if (!FULL && (lgl >= L || sgl >= L)) wgt = 0.f;
          a[e] = f2bf(cbv * wgt * dss[e]);
        }
#pragma unroll
        for (int j = 0; j < 4; ++j)
          yacc[i][j] = __builtin_amdgcn_mfma_f32_16x16x32_bf16(a, bx[ks][j], yacc[i][j], 0, 0, 0);
      }
    }
    if (c + 1 < NCH) __syncthreads();
  }

#pragma unroll
  for (int i = 0; i < 4; ++i)
#pragma unroll
    for (int rr = 0; rr < 4; ++rr) {
      int lgl = l0 + i * 16 + lg * 4 + rr;
      if (FULL || lgl < L) {
        short* yp = y + ((long)seq * L + lgl) * 512 + h * 64 + lr;
#pragma unroll
        for (int j = 0; j < 4; ++j) yp[j * 16] = f2bf(yacc[i][j][rr]);
      }
    }
}

// ---------------- gate: ybh = rmsnorm((y + D*xh) * silu(z)) * gn_w  (bf16 out)
__global__ __launch_bounds__(256) void k_gate2(const short* __restrict__ y,
                                               const short* __restrict__ zxh,
                                               const short* __restrict__ xbc,
                                               const float* __restrict__ Dp,
                                               const float* __restrict__ gnw,
                                               short* __restrict__ ybh) {
  int m = blockIdx.x * 4 + (threadIdx.x >> 6);
  int lane = threadIdx.x & 63;
  int d0 = lane * 8;
  short8v yv = *(const short8v*)(y + (long)m * 512 + d0);
  short8v xv = *(const short8v*)(xbc + (long)m * 640 + d0);
  short8v zv = *(const short8v*)(zxh + (long)m * ZXW + d0);
  float Dh = Dp[lane >> 3];
  float g[8];
  float ss = 0.f;
#pragma unroll
  for (int i = 0; i < 8; ++i) {
    float zi = bf2f(zv[i]);
    g[i] = (bf2f(yv[i]) + Dh * bf2f(xv[i])) * zi / (1.f + __expf(-zi));
    ss += g[i] * g[i];
  }
  ss = wave_sum64(ss);
  float scl = rsqrtf(ss * (1.f / 512.f) + 1e-6f);
  short8v o;
#pragma unroll
  for (int i = 0; i < 8; ++i) o[i] = f2bf(g[i] * scl * gnw[d0 + i]);
  *(short8v*)(ybh + (long)m * 512 + d0) = o;
}

extern "C" void kernel_launch(void* const* d_in, const int* in_sizes, int n_in,
                              void* d_out, int out_size, void* d_ws, size_t ws_size,
                              hipStream_t stream) {
  (void)in_sizes; (void)n_in; (void)out_size; (void)ws_size;
  const float* x = (const float*)d_in[0];
  float* out = (float*)d_out;
  const long M = MTOK;

  char* p = (char*)d_ws;
  short* zxh = (short*)p;    p += (size_t)M * ZXW * 2;         // 54.9 MB
  float* dtraw = (float*)p;  p += (size_t)M * 8 * 4;
  short* bufn = (short*)p;   p += (size_t)M * 256 * 2;         // 12.2 MB
  short* xbc = (short*)p;    p += (size_t)M * 640 * 2 + 4096;  // 30.5 MB
  float* dtb = (float*)p;    p += (size_t)M * 8 * 4;
  float* cumb = (float*)p;   p += (size_t)M * 8 * 4;
  short* ybuf = (short*)p;   p += (size_t)M * 512 * 2;         // 24.4 MB
  short* xT = (short*)p;     p += (size_t)12582912 * 2;        // 25.2 MB
  short* ybh = (short*)p;    p += (size_t)M * 512 * 2;         // 24.4 MB
  short* WinT = (short*)p;   p += (size_t)4 * PROJP * 256 * 2; // 2.6 MB
  short* WoutT = (short*)p;  p += (size_t)4 * 256 * 512 * 2;   // 1.0 MB

  // weight prep (every call; deterministic)
  k_wt<<<dim3((PROJP * 256 + 255) / 256, 1, 4), 256, 0, stream>>>(
      (const float*)d_in[2], (const float*)d_in[11], WinT, 256, 1160, PROJP);
  k_wt<<<dim3((256 * 512 + 255) / 256, 1, 4), 256, 0, stream>>>(
      (const float*)d_in[9], (const float*)d_in[18], WoutT, 512, 256, 256);

  hipMemcpyAsync(out, x, (size_t)M * 256 * sizeof(float), hipMemcpyDeviceToDevice, stream);

  for (int layer = 0; layer < 2; ++layer) {
    for (int path = 0; path < 2; ++path) {
      const float* const* P = (const float* const*)(d_in + 1 + path * 9);
      const float* nw = P[0] + layer * 256;
      const float* Wc = P[2] + layer * 640 * 4;
      const float* bc = P[3] + layer * 640;
      const float* dtbias = P[4] + layer * 8;
      const float* Alog = P[5] + layer * 8;
      const float* Dp = P[6] + layer * 8;
      const float* gnw = P[7] + layer * 512;
      const short* WinTp = WinT + (long)(path * 2 + layer) * PROJP * 256;
      const short* WoutTp = WoutT + (long)(path * 2 + layer) * 256 * 512;
      int L = (path == 0) ? 192 : 62;
      int nseq = (path == 0) ? 124 : 384;

      if (path == 0) k_rmsnorm_in<true><<<MTOK / 4, 256, 0, stream>>>(out, nw, bufn);
      else           k_rmsnorm_in<false><<<MTOK / 4, 256, 0, stream>>>(out, nw, bufn);

      gemm_in<<<dim3(10, MTOK / 128), 256, 0, stream>>>(bufn, WinTp, zxh, dtraw);

      k_conv<<<(MTOK * 80 + 255) / 256, 256, 0, stream>>>(zxh, Wc, bc, xbc, L);
      k_scan<<<(nseq * 8 + 3) / 4, 256, 0, stream>>>(dtraw, dtbias, Alog, dtb, cumb, nseq, L);

      if (path == 0) k_xt<192><<<dim3(nseq, 8, 3), 256, 0, stream>>>(xbc, xT);
      else           k_xt<62><<<dim3(nseq, 8, 1), 256, 0, stream>>>(xbc, xT);

      if (path == 0) k_ssd4<192, 3><<<dim3(2, 3, nseq), 256, 0, stream>>>(xbc, xT, dtb, cumb, Alog, ybuf);
      else           k_ssd4<62, 1><<<dim3(2, 1, nseq), 256, 0, stream>>>(xbc, xT, dtb, cumb, Alog, ybuf);

      k_gate2<<<MTOK / 4, 256, 0, stream>>>(ybuf, zxh, xbc, Dp, gnw, ybh);

      if (path == 0) gemm_mfma<1><<<dim3(2, MTOK / 128), 256, 0, stream>>>(ybh, WoutTp, out, 512, 0);
      else           gemm_mfma<2><<<dim3(2, MTOK / 128), 256, 0, stream>>>(ybh, WoutTp, out, 512, 0);
    }
  }
}

// Round 8
// 1007.714 us; speedup vs baseline: 1.0519x; 1.0519x over previous
//
#include <hip/hip_runtime.h>
#include <hip/hip_bf16.h>

// DualPathModule: 2 layers x (t-path, b-path) Mamba2, bf16-MFMA version.
// HID=256, DIN=512, NHEADS=8, HEADP=64, DSTATE=64, CONVDIM=640, PROJ=1160 (padded 1280)
// t-path: 124 seqs x L=192 (strided in x); b-path: 384 seqs x L=62. M=23808.
// inproj output: zxh bf16 [M x 1152] (z 0..511 | conv-in 512..1151) + dtraw f32 [M x 8].

#define MTOK   23808
#define PROJP  1280   // padded WinT rows (cols 1160..1279 zero)
#define ZXW    1152   // zxh row stride (bf16)

typedef __attribute__((ext_vector_type(8))) short short8v;
typedef __attribute__((ext_vector_type(4))) short short4v;
typedef __attribute__((ext_vector_type(4))) float f32x4;

__device__ __forceinline__ float wave_sum64(float v) {
#pragma unroll
  for (int off = 32; off; off >>= 1) v += __shfl_xor(v, off, 64);
  return v;
}

__device__ __forceinline__ short f2bf(float f) {
  union { float f; unsigned u; } v; v.f = f;
  unsigned r = (v.u + 0x7fffu + ((v.u >> 16) & 1u)) >> 16;  // RNE
  return (short)r;
}
__device__ __forceinline__ float bf2f(short s) {
  union { unsigned u; float f; } v; v.u = ((unsigned)(unsigned short)s) << 16; return v.f;
}

// token m of t-path (seq = b*62+nb, time tt) -> flat offset in x (B,T,NB,H)
__device__ __forceinline__ long t_base(int m) {
  int seq = m / 192, tt = m - seq * 192;
  int b = seq / 62, nb = seq - b * 62;
  return ((long)((b * 192 + tt) * 62 + nb)) * 256;
}

// bijective XCD chunk swizzle (m204): consecutive work chunks land on one XCD's L2
__device__ __forceinline__ int xcd_swz(int bid, int nwg) {
  int q = nwg >> 3, r = nwg & 7;
  int xcd = bid & 7, idx = bid >> 3;
  return (xcd < r ? xcd * (q + 1) : r * (q + 1) + (xcd - r) * q) + idx;
}

// ---------------- weight transpose+cvt: dst[z][n][k] = src_z[k][n], n>=N zero-padded
__global__ __launch_bounds__(256) void k_wt(const float* __restrict__ tW,
                                            const float* __restrict__ bW,
                                            short* __restrict__ dst, int K, int N, int NP) {
  int z = blockIdx.z;
  const float* src = (z >> 1 ? bW : tW) + (long)(z & 1) * K * N;
  short* d = dst + (long)z * NP * K;
  int idx = blockIdx.x * 256 + threadIdx.x;
  if (idx >= NP * K) return;
  int n = idx / K, k = idx - n * K;
  d[idx] = (n < N) ? f2bf(src[(long)k * N + n]) : (short)0;
}

// ---------------- gather + rmsnorm over H=256 -> bufn[M x 256] bf16
template <bool TPATH>
__global__ __launch_bounds__(256) void k_rmsnorm_in(const float* __restrict__ xio,
                                                    const float* __restrict__ w,
                                                    short* __restrict__ outb) {
  int m = blockIdx.x * 4 + (threadIdx.x >> 6);
  int lane = threadIdx.x & 63;
  long base = TPATH ? t_base(m) : (long)m * 256;
  float4 v = *(const float4*)(xio + base + lane * 4);
  float ss = v.x * v.x + v.y * v.y + v.z * v.z + v.w * v.w;
  ss = wave_sum64(ss);
  float sc = rsqrtf(ss * (1.f / 256.f) + 1e-6f);
  float4 wv = *(const float4*)(w + lane * 4);
  short4v o;
  o[0] = f2bf(v.x * sc * wv.x); o[1] = f2bf(v.y * sc * wv.y);
  o[2] = f2bf(v.z * sc * wv.z); o[3] = f2bf(v.w * sc * wv.w);
  *(short4v*)(outb + (long)m * 256 + lane * 4) = o;
}

// ---------------- inproj GEMM v2: 1-wave blocks, 64x64/wave, reg-dbuf k-loop,
// LDS-transposed coalesced bf16 epilogue. grid (19, 372): n-tiles 0..17 -> zxh,
// tile 18 -> dt cols (f32 to dtraw).
__global__ __launch_bounds__(64) void gemm_in2(const short* __restrict__ A,
                                               const short* __restrict__ WT,
                                               short* __restrict__ zxh,
                                               float* __restrict__ dtraw) {
  __shared__ short s_t[64][72];  // 9.2 KB, rows 16B-aligned (144B stride)
  int bid = blockIdx.y * 19 + blockIdx.x;
  int wg = xcd_swz(bid, 19 * 372);
  int bx = wg % 19, by = wg / 19;
  int m0 = by * 64, n0 = bx * 64;
  int lane = threadIdx.x;
  int lr = lane & 15, lg = lane >> 4;

  f32x4 acc[4][4];
#pragma unroll
  for (int i = 0; i < 4; ++i)
#pragma unroll
    for (int j = 0; j < 4; ++j) acc[i][j] = (f32x4){0.f, 0.f, 0.f, 0.f};

  const short* Ap = A + (long)(m0 + lr) * 256 + lg * 8;
  const short* Bp = WT + (long)(n0 + lr) * 256 + lg * 8;

  short8v a[2][4], b[2][4];
#pragma unroll
  for (int f = 0; f < 4; ++f) {
    a[0][f] = *(const short8v*)(Ap + f * 16 * 256);
    b[0][f] = *(const short8v*)(Bp + f * 16 * 256);
  }
#pragma unroll
  for (int k = 0; k < 8; ++k) {
    const int cur = k & 1, nxt = cur ^ 1;
    if (k < 7) {
#pragma unroll
      for (int f = 0; f < 4; ++f) {
        a[nxt][f] = *(const short8v*)(Ap + f * 16 * 256 + (k + 1) * 32);
        b[nxt][f] = *(const short8v*)(Bp + f * 16 * 256 + (k + 1) * 32);
      }
    }
#pragma unroll
    for (int i = 0; i < 4; ++i)
#pragma unroll
      for (int j = 0; j < 4; ++j)
        acc[i][j] = __builtin_amdgcn_mfma_f32_16x16x32_bf16(a[cur][i], b[cur][j], acc[i][j], 0, 0, 0);
  }

  if (n0 < ZXW) {
    // transpose through LDS, then coalesced 16B row stores
#pragma unroll
    for (int i = 0; i < 4; ++i)
#pragma unroll
      for (int j = 0; j < 4; ++j)
#pragma unroll
        for (int rr = 0; rr < 4; ++rr)
          s_t[i * 16 + lg * 4 + rr][j * 16 + lr] = f2bf(acc[i][j][rr]);
    __syncthreads();
#pragma unroll
    for (int rb = 0; rb < 8; ++rb) {
      int row = rb * 8 + (lane >> 3);
      short8v v = *(const short8v*)&s_t[row][(lane & 7) * 8];
      *(short8v*)(zxh + (long)(m0 + row) * ZXW + n0 + (lane & 7) * 8) = v;
    }
  } else {
    // dt tile: cols 1152..1159 (j=0, lr<8) -> dtraw f32
    if (lr < 8) {
#pragma unroll
      for (int i = 0; i < 4; ++i)
#pragma unroll
        for (int rr = 0; rr < 4; ++rr)
          dtraw[(long)(m0 + i * 16 + lg * 4 + rr) * 8 + lr] = acc[i][0][rr];
    }
  }
}

// ---------------- outproj GEMM v2 + residual. 1-wave blocks, 64x64/wave,
// reg-dbuf K=512, LDS-transposed float4 RMW epilogue. EPI 1 = t-path, 2 = b.
template <int EPI>
__global__ __launch_bounds__(64) void gemm_out2(const short* __restrict__ A,
                                                const short* __restrict__ WT,
                                                float* __restrict__ C) {
  __shared__ float s_t[64][68];  // 17.4 KB, rows 16B-aligned (272B stride)
  int bid = blockIdx.y * 4 + blockIdx.x;
  int wg = xcd_swz(bid, 4 * 372);
  int bx = wg & 3, by = wg >> 2;
  int m0 = by * 64, n0 = bx * 64;
  int lane = threadIdx.x;
  int lr = lane & 15, lg = lane >> 4;

  f32x4 acc[4][4];
#pragma unroll
  for (int i = 0; i < 4; ++i)
#pragma unroll
    for (int j = 0; j < 4; ++j) acc[i][j] = (f32x4){0.f, 0.f, 0.f, 0.f};

  const short* Ap = A + (long)(m0 + lr) * 512 + lg * 8;
  const short* Bp = WT + (long)(n0 + lr) * 512 + lg * 8;

  short8v a[2][4], b[2][4];
#pragma unroll
  for (int f = 0; f < 4; ++f) {
    a[0][f] = *(const short8v*)(Ap + f * 16 * 512);
    b[0][f] = *(const short8v*)(Bp + f * 16 * 512);
  }
#pragma unroll
  for (int k = 0; k < 16; ++k) {
    const int cur = k & 1, nxt = cur ^ 1;
    if (k < 15) {
#pragma unroll
      for (int f = 0; f < 4; ++f) {
        a[nxt][f] = *(const short8v*)(Ap + f * 16 * 512 + (k + 1) * 32);
        b[nxt][f] = *(const short8v*)(Bp + f * 16 * 512 + (k + 1) * 32);
      }
    }
#pragma unroll
    for (int i = 0; i < 4; ++i)
#pragma unroll
      for (int j = 0; j < 4; ++j)
        acc[i][j] = __builtin_amdgcn_mfma_f32_16x16x32_bf16(a[cur][i], b[cur][j], acc[i][j], 0, 0, 0);
  }

#pragma unroll
  for (int i = 0; i < 4; ++i)
#pragma unroll
    for (int j = 0; j < 4; ++j)
#pragma unroll
      for (int rr = 0; rr < 4; ++rr)
        s_t[i * 16 + lg * 4 + rr][j * 16 + lr] = acc[i][j][rr];
  __syncthreads();
#pragma unroll
  for (int rb = 0; rb < 16; ++rb) {
    int row = rb * 4 + (lane >> 4);
    f32x4 v = *(const f32x4*)&s_t[row][lr * 4];
    int m = m0 + row;
    long base = (EPI == 1) ? t_base(m) : (long)m * 256;
    float* cp = C + base + n0 + lr * 4;
    float4 old = *(const float4*)cp;
    *(float4*)cp = make_float4(old.x + v[0], old.y + v[1], old.z + v[2], old.w + v[3]);
  }
}

// ---------------- causal depthwise conv(K=4) + silu, bf16 in -> xBC[M x 640] bf16
// 1 thread = 8 consecutive channels (short8v loads/store)
__global__ __launch_bounds__(256) void k_conv(const short* __restrict__ zin,
                                              const float* __restrict__ Wc,
                                              const float* __restrict__ bc,
                                              short* __restrict__ xBC, int L) {
  int idx = blockIdx.x * 256 + threadIdx.x;
  if (idx >= MTOK * 80) return;
  int m = idx / 80, c8 = (idx - m * 80) << 3;
  int tpos = m % L;
  float wv[8][4];
#pragma unroll
  for (int e = 0; e < 8; ++e) {
    float4 we = *(const float4*)(Wc + (c8 + e) * 4);
    wv[e][0] = we.x; wv[e][1] = we.y; wv[e][2] = we.z; wv[e][3] = we.w;
  }
  float acc[8];
  float4 b0 = *(const float4*)(bc + c8);
  float4 b1 = *(const float4*)(bc + c8 + 4);
  acc[0] = b0.x; acc[1] = b0.y; acc[2] = b0.z; acc[3] = b0.w;
  acc[4] = b1.x; acc[5] = b1.y; acc[6] = b1.z; acc[7] = b1.w;
  const short* base = zin + (long)m * ZXW + 512 + c8;
#pragma unroll
  for (int k = 0; k < 4; ++k) {
    int tt = tpos - 3 + k;
    if (tt >= 0) {
      short8v v = *(const short8v*)(base + (long)(k - 3) * ZXW);
#pragma unroll
      for (int e = 0; e < 8; ++e) acc[e] += wv[e][k] * bf2f(v[e]);
    }
  }
  short8v o;
#pragma unroll
  for (int e = 0; e < 8; ++e) o[e] = f2bf(acc[e] / (1.f + __expf(-acc[e])));
  *(short8v*)(xBC + (long)m * 640 + c8) = o;
}

// ---------------- fused softplus(dt) + per-(seq,head) inclusive scan of dt*A
__global__ __launch_bounds__(256) void k_scan(const float* __restrict__ dtraw,
                                              const float* __restrict__ dtbias,
                                              const float* __restrict__ A_log,
                                              float* __restrict__ dtb,
                                              float* __restrict__ cumb,
                                              int nseq, int L) {
  int wid = blockIdx.x * 4 + (threadIdx.x >> 6);
  if (wid >= nseq * 8) return;
  int seq = wid >> 3, h = wid & 7, lane = threadIdx.x & 63;
  float Ah = -__expf(A_log[h]);
  float bias = dtbias[h];
  float run = 0.f;
  for (int t0 = 0; t0 < L; t0 += 64) {
    int tt = t0 + lane;
    float d = 0.f;
    if (tt < L) {
      float v = dtraw[((long)seq * L + tt) * 8 + h] + bias;
      d = (v > 20.f) ? v : log1pf(__expf(v));
    }
    float s = d * Ah;
#pragma unroll
    for (int off = 1; off < 64; off <<= 1) {
      float o = __shfl_up(s, off, 64);
      if (lane >= off) s += o;
    }
    if (tt < L) {
      long m = (long)seq * L + tt;
      dtb[m * 8 + h] = d;
      cumb[m * 8 + h] = run + s;
    }
    run += __shfl(s, 63, 64);
  }
}

// ---------------- x transpose: xT[(seq*8+h)*64 + p][LP] = x[s][h*64+p], zero-padded s>=L
template <int L>
__global__ __launch_bounds__(256) void k_xt(const short* __restrict__ xbc,
                                            short* __restrict__ xT) {
  constexpr int LP = (L + 63) & ~63;
  int seq = blockIdx.x, h = blockIdx.y, st = blockIdx.z;
  __shared__ short tile[64][72];
  int t = threadIdx.x;
  for (int e = t; e < 512; e += 256) {
    int s = e >> 3, p8 = (e & 7) * 8;
    int sg = st * 64 + s;
    union { short8v v; short a[8]; } u;
    if (sg < L) u.v = *(const short8v*)(xbc + ((long)seq * L + sg) * 640 + h * 64 + p8);
    else {
#pragma unroll
      for (int j = 0; j < 8; ++j) u.a[j] = 0;
    }
    *(short8v*)&tile[s][p8] = u.v;
  }
  __syncthreads();
  for (int e = t; e < 512; e += 256) {
    int p = e >> 3, s8 = (e & 7) * 8;
    union { short8v v; short a[8]; } u;
#pragma unroll
    for (int j = 0; j < 8; ++j) u.a[j] = tile[s8 + j][p];
    *(short8v*)(xT + ((long)(seq * 8 + h) * 64 + p) * LP + st * 64 + s8) = u.v;
  }
}

// ---------------- SSD v4: shared-CB, in-register P. (unchanged)
template <int L, int NCH>
__global__ __launch_bounds__(256) void k_ssd4(const short* __restrict__ xbc,
                                              const short* __restrict__ xT,
                                              const float* __restrict__ dtb,
                                              const float* __restrict__ cumb,
                                              const float* __restrict__ A_log,
                                              short* __restrict__ y) {
  constexpr int LP = (L + 63) & ~63;
  constexpr bool FULL = (L % 64) == 0;
  int hg = blockIdx.x, lt = blockIdx.y, seq = blockIdx.z;
  int tid = threadIdx.x, w = tid >> 6, lane = tid & 63;
  int lr = lane & 15, lg = lane >> 4;
  int h = hg * 4 + w;
  int l0 = lt * 64;

  __shared__ float s_cb[64 * 64];     // [l][s ^ ((l&7)<<2)] f32, 16KB
  __shared__ float s_cums[64][8];
  __shared__ float s_dts[64][8];

  float Ah = -__expf(A_log[h]);

  float cl[4], cpl[4];
#pragma unroll
  for (int i = 0; i < 4; ++i) {
    int lgl = l0 + i * 16 + lr;
    int lc = FULL ? lgl : (lgl < L ? lgl : L - 1);
    long m = (long)seq * L + lc;
    float cv = cumb[m * 8 + h];
    cl[i] = cv; cpl[i] = cv - dtb[m * 8 + h] * Ah;
  }

  f32x4 yacc[4][4];
#pragma unroll
  for (int i = 0; i < 4; ++i)
#pragma unroll
    for (int j = 0; j < 4; ++j) yacc[i][j] = (f32x4){0.f, 0.f, 0.f, 0.f};

  int crow = l0 + w * 16 + lr;
  if (!FULL) crow = crow < L ? crow : L - 1;
  const short* Cp = xbc + ((long)seq * L + crow) * 640 + 576 + lg * 8;

  for (int c = 0; c < NCH; ++c) {
    int c64 = c * 64;

    if (tid < 128) {
      int rr = tid & 63;
      int sg = c64 + rr;
      int sc = FULL ? sg : (sg < L ? sg : L - 1);
      const float* src = (tid < 64 ? cumb : dtb) + ((long)seq * L + sc) * 8;
      float4 v0 = *(const float4*)(src);
      float4 v1 = *(const float4*)(src + 4);
      float* dstp = (tid < 64 ? &s_cums[rr][0] : &s_dts[rr][0]);
      *(float4*)dstp = v0;
      *(float4*)(dstp + 4) = v1;
    }

    f32x4 cb4[4];
#pragma unroll
    for (int j = 0; j < 4; ++j) cb4[j] = (f32x4){0.f, 0.f, 0.f, 0.f};
#pragma unroll
    for (int ks = 0; ks < 2; ++ks) {
      short8v a = *(const short8v*)(Cp + ks * 32);
#pragma unroll
      for (int j = 0; j < 4; ++j) {
        int srow = c64 + j * 16 + lr;
        if (!FULL) srow = srow < L ? srow : L - 1;
        short8v b = *(const short8v*)(xbc + ((long)seq * L + srow) * 640 + 512 + lg * 8 + ks * 32);
        cb4[j] = __builtin_amdgcn_mfma_f32_16x16x32_bf16(a, b, cb4[j], 0, 0, 0);
      }
    }
#pragma unroll
    for (int j = 0; j < 4; ++j)
#pragma unroll
      for (int rr = 0; rr < 4; ++rr) {
        int lloc = w * 16 + lg * 4 + rr;
        int sloc = j * 16 + lr;
        s_cb[lloc * 64 + (sloc ^ ((lloc & 7) << 2))] = cb4[j][rr];
      }

    short8v bx[2][4];
#pragma unroll
    for (int ks = 0; ks < 2; ++ks)
#pragma unroll
      for (int j = 0; j < 4; ++j)
        bx[ks][j] = *(const short8v*)(xT + ((long)(seq * 8 + h) * 64 + j * 16 + lr) * LP +
                                      c64 + ks * 32 + lg * 8);

    __syncthreads();

#pragma unroll
    for (int ks = 0; ks < 2; ++ks) {
      int sbase = ks * 32 + lg * 8;
      float cs[8], cps[8], dss[8];
#pragma unroll
      for (int e = 0; e < 8; ++e) {
        int sl = sbase + e;
        float cv = s_cums[sl][h];
        float dv = s_dts[sl][h];
        cs[e] = cv; cps[e] = cv - dv * Ah; dss[e] = dv;
      }
#pragma unroll
      for (int i = 0; i < 4; ++i) {
        int R = i * 16 + lr;
        int lgl = l0 + R;
        int sw = (R & 7) << 2;
        int c0 = sbase ^ sw;
        const float* cbrow = &s_cb[R * 64];
        f32x4 lo = *(const f32x4*)(cbrow + c0);
        f32x4 hi = *(const f32x4*)(cbrow + (c0 ^ 4));
        short8v a;
#pragma unroll
        for (int e = 0; e < 8; ++e) {
          int sgl = c64 + sbase + e;
          float cbv = (e < 4) ? lo[e & 3] : hi[e & 3];
          float wgt = 0.f;
          if (sgl <= lgl) wgt += __expf(cl[i] - cs[e]);
          if (sgl >= lgl) wgt += __expf(cps[e] - cpl[i]);
          if (!FULL && (lgl >= L || sgl >= L)) wgt = 0.f;
          a[e] = f2bf(cbv * wgt * dss[e]);
        }
#pragma unroll
        for (int j = 0; j < 4; ++j)
          yacc[i][j] = __builtin_amdgcn_mfma_f32_16x16x32_bf16(a, bx[ks][j], yacc[i][j], 0, 0, 0);
      }
    }
    if (c + 1 < NCH) __syncthreads();
  }

#pragma unroll
  for (int i = 0; i < 4; ++i)
#pragma unroll
    for (int rr = 0; rr < 4; ++rr) {
      int lgl = l0 + i * 16 + lg * 4 + rr;
      if (FULL || lgl < L) {
        short* yp = y + ((long)seq * L + lgl) * 512 + h * 64 + lr;
#pragma unroll
        for (int j = 0; j < 4; ++j) yp[j * 16] = f2bf(yacc[i][j][rr]);
      }
    }
}

// ---------------- gate: ybh = rmsnorm((y + D*xh) * silu(z)) * gn_w  (bf16 out)
__global__ __launch_bounds__(256) void k_gate2(const short* __restrict__ y,
                                               const short* __restrict__ zxh,
                                               const short* __restrict__ xbc,
                                               const float* __restrict__ Dp,
                                               const float* __restrict__ gnw,
                                               short* __restrict__ ybh) {
  int m = blockIdx.x * 4 + (threadIdx.x >> 6);
  int lane = threadIdx.x & 63;
  int d0 = lane * 8;
  short8v yv = *(const short8v*)(y + (long)m * 512 + d0);
  short8v xv = *(const short8v*)(xbc + (long)m * 640 + d0);
  short8v zv = *(const short8v*)(zxh + (long)m * ZXW + d0);
  float Dh = Dp[lane >> 3];
  float g[8];
  float ss = 0.f;
#pragma unroll
  for (int i = 0; i < 8; ++i) {
    float zi = bf2f(zv[i]);
    g[i] = (bf2f(yv[i]) + Dh * bf2f(xv[i])) * zi / (1.f + __expf(-zi));
    ss += g[i] * g[i];
  }
  ss = wave_sum64(ss);
  float scl = rsqrtf(ss * (1.f / 512.f) + 1e-6f);
  short8v o;
#pragma unroll
  for (int i = 0; i < 8; ++i) o[i] = f2bf(g[i] * scl * gnw[d0 + i]);
  *(short8v*)(ybh + (long)m * 512 + d0) = o;
}

extern "C" void kernel_launch(void* const* d_in, const int* in_sizes, int n_in,
                              void* d_out, int out_size, void* d_ws, size_t ws_size,
                              hipStream_t stream) {
  (void)in_sizes; (void)n_in; (void)out_size; (void)ws_size;
  const float* x = (const float*)d_in[0];
  float* out = (float*)d_out;
  const long M = MTOK;

  char* p = (char*)d_ws;
  short* zxh = (short*)p;    p += (size_t)M * ZXW * 2;         // 54.9 MB
  float* dtraw = (float*)p;  p += (size_t)M * 8 * 4;
  short* bufn = (short*)p;   p += (size_t)M * 256 * 2;         // 12.2 MB
  short* xbc = (short*)p;    p += (size_t)M * 640 * 2 + 4096;  // 30.5 MB
  float* dtb = (float*)p;    p += (size_t)M * 8 * 4;
  float* cumb = (float*)p;   p += (size_t)M * 8 * 4;
  short* ybuf = (short*)p;   p += (size_t)M * 512 * 2;         // 24.4 MB
  short* xT = (short*)p;     p += (size_t)12582912 * 2;        // 25.2 MB
  short* ybh = (short*)p;    p += (size_t)M * 512 * 2;         // 24.4 MB
  short* WinT = (short*)p;   p += (size_t)4 * PROJP * 256 * 2; // 2.6 MB
  short* WoutT = (short*)p;  p += (size_t)4 * 256 * 512 * 2;   // 1.0 MB

  // weight prep (every call; deterministic)
  k_wt<<<dim3((PROJP * 256 + 255) / 256, 1, 4), 256, 0, stream>>>(
      (const float*)d_in[2], (const float*)d_in[11], WinT, 256, 1160, PROJP);
  k_wt<<<dim3((256 * 512 + 255) / 256, 1, 4), 256, 0, stream>>>(
      (const float*)d_in[9], (const float*)d_in[18], WoutT, 512, 256, 256);

  hipMemcpyAsync(out, x, (size_t)M * 256 * sizeof(float), hipMemcpyDeviceToDevice, stream);

  for (int layer = 0; layer < 2; ++layer) {
    for (int path = 0; path < 2; ++path) {
      const float* const* P = (const float* const*)(d_in + 1 + path * 9);
      const float* nw = P[0] + layer * 256;
      const float* Wc = P[2] + layer * 640 * 4;
      const float* bc = P[3] + layer * 640;
      const float* dtbias = P[4] + layer * 8;
      const float* Alog = P[5] + layer * 8;
      const float* Dp = P[6] + layer * 8;
      const float* gnw = P[7] + layer * 512;
      const short* WinTp = WinT + (long)(path * 2 + layer) * PROJP * 256;
      const short* WoutTp = WoutT + (long)(path * 2 + layer) * 256 * 512;
      int L = (path == 0) ? 192 : 62;
      int nseq = (path == 0) ? 124 : 384;

      if (path == 0) k_rmsnorm_in<true><<<MTOK / 4, 256, 0, stream>>>(out, nw, bufn);
      else           k_rmsnorm_in<false><<<MTOK / 4, 256, 0, stream>>>(out, nw, bufn);

      gemm_in2<<<dim3(19, MTOK / 64), 64, 0, stream>>>(bufn, WinTp, zxh, dtraw);

      k_conv<<<(MTOK * 80 + 255) / 256, 256, 0, stream>>>(zxh, Wc, bc, xbc, L);
      k_scan<<<(nseq * 8 + 3) / 4, 256, 0, stream>>>(dtraw, dtbias, Alog, dtb, cumb, nseq, L);

      if (path == 0) k_xt<192><<<dim3(nseq, 8, 3), 256, 0, stream>>>(xbc, xT);
      else           k_xt<62><<<dim3(nseq, 8, 1), 256, 0, stream>>>(xbc, xT);

      if (path == 0) k_ssd4<192, 3><<<dim3(2, 3, nseq), 256, 0, stream>>>(xbc, xT, dtb, cumb, Alog, ybuf);
      else           k_ssd4<62, 1><<<dim3(2, 1, nseq), 256, 0, stream>>>(xbc, xT, dtb, cumb, Alog, ybuf);

      k_gate2<<<MTOK / 4, 256, 0, stream>>>(ybuf, zxh, xbc, Dp, gnw, ybh);

      if (path == 0) gemm_out2<1><<<dim3(4, MTOK / 64), 64, 0, stream>>>(ybh, WoutTp, out);
      else           gemm_out2<2><<<dim3(4, MTOK / 64), 64, 0, stream>>>(ybh, WoutTp, out);
    }
  }
}